// Round 1
// baseline (812.801 us; speedup 1.0000x reference)
//
#include <hip/hip_runtime.h>
#include <hip/hip_bf16.h>

#define T_LEN   16000
#define NT4     4000        // T_LEN/4
#define C_IN    256
#define C_MID   128
#define NB      16
#define NTB     125         // T_LEN / 128
#define EPSV    1e-8f

// ---------------------------------------------------------------------------
// Kernel A: per-(b,c) row sums s = sum(x), q = sum(x^2).  4096 blocks.
// ---------------------------------------------------------------------------
__global__ __launch_bounds__(256) void kA_rowstats(
    const float* __restrict__ x, float* __restrict__ s, float* __restrict__ q)
{
    const int row = blockIdx.x;                 // b*256 + c
    const float4* x4 = (const float4*)(x + (size_t)row * T_LEN);
    float ss = 0.f, qq = 0.f;
    for (int i = threadIdx.x; i < NT4; i += 256) {
        float4 v = x4[i];
        ss += v.x + v.y + v.z + v.w;
        qq += v.x*v.x + v.y*v.y + v.z*v.z + v.w*v.w;
    }
    #pragma unroll
    for (int off = 32; off; off >>= 1) {
        ss += __shfl_down(ss, off, 64);
        qq += __shfl_down(qq, off, 64);
    }
    __shared__ float rs[4], rq[4];
    const int wid = threadIdx.x >> 6, lane = threadIdx.x & 63;
    if (lane == 0) { rs[wid] = ss; rq[wid] = qq; }
    __syncthreads();
    if (threadIdx.x == 0) {
        s[row] = rs[0] + rs[1] + rs[2] + rs[3];
        q[row] = rq[0] + rq[1] + rq[2] + rq[3];
    }
}

// ---------------------------------------------------------------------------
// block-wide sum over 256 threads
// ---------------------------------------------------------------------------
__device__ __forceinline__ float blockSum256(float v, float* red)
{
    #pragma unroll
    for (int off = 32; off; off >>= 1) v += __shfl_down(v, off, 64);
    __syncthreads();
    if ((threadIdx.x & 63) == 0) red[threadIdx.x >> 6] = v;
    __syncthreads();
    return red[0] + red[1] + red[2] + red[3];
}

// ---------------------------------------------------------------------------
// Kernel B: per-batch analytic composition through GN1,GN2,film1,GN3,conv1,
// film2.  Produces M[b][128][256] (z2 = M x + e) and e[b][128].
// One block (256 threads) per batch.
// ---------------------------------------------------------------------------
__global__ __launch_bounds__(256) void kB_compose(
    const float* __restrict__ s,      const float* __restrict__ q,
    const float* __restrict__ cue,
    const float* __restrict__ gn_a_w, const float* __restrict__ gn_a_b,
    const float* __restrict__ gn_n_w, const float* __restrict__ gn_n_b,
    const float* __restrict__ f1g_w,  const float* __restrict__ f1g_b,
    const float* __restrict__ f1b_w,  const float* __restrict__ f1b_b,
    const float* __restrict__ ln1_w,  const float* __restrict__ ln1_b,
    const float* __restrict__ conv1_w,const float* __restrict__ cds_w,
    const float* __restrict__ f2g_w,  const float* __restrict__ f2g_b,
    const float* __restrict__ f2b_w,  const float* __restrict__ f2b_b,
    float* __restrict__ Mout, float* __restrict__ eout)
{
    const int b = blockIdx.x;
    const int c = threadIdx.x;           // channel, 0..255
    __shared__ float red[4];
    __shared__ float sh_cue[512];
    __shared__ float sh_a[256], sh_d[256], sh_cue2[256], sh_g2[128];

    sh_cue[c]       = cue[b*512 + c];
    sh_cue[256 + c] = cue[b*512 + 256 + c];
    const float sc = s[b*256 + c];
    const float qc = q[b*256 + c];
    __syncthreads();

    const float Ninv = 1.f / (256.f * 16000.f);
    const float Tf = 16000.f;

    // GN 1 (gn_a)
    float S  = blockSum256(sc, red);
    float Q  = blockSum256(qc, red);
    float mu1 = S * Ninv;
    float var1 = Q * Ninv - mu1 * mu1;
    float r1 = rsqrtf(var1 + EPSV);
    float a1 = gn_a_w[c] * r1;
    float d1 = gn_a_b[c] - mu1 * r1 * gn_a_w[c];

    // GN 2 (gn_n) on y1 = a1*x + d1
    float S2 = blockSum256(a1*sc + Tf*d1, red);
    float Q2 = blockSum256(a1*a1*qc + 2.f*a1*d1*sc + Tf*d1*d1, red);
    float mu2 = S2 * Ninv;
    float var2 = Q2 * Ninv - mu2 * mu2;
    float r2 = rsqrtf(var2 + EPSV);
    float wn = gn_n_w[c];
    float a2 = wn * r2 * a1;
    float d2 = wn * r2 * (d1 - mu2) + gn_n_b[c];

    // film1 (+ residual): (1+g1)*y2 + b1
    float g1 = f1g_b[c], b1 = f1b_b[c];
    for (int k = 0; k < 512; ++k) {
        const float cv = sh_cue[k];
        g1 = fmaf(cv, f1g_w[c*512 + k], g1);
        b1 = fmaf(cv, f1b_w[c*512 + k], b1);
    }
    g1 = fmaxf(g1, 0.f) + 1.f;
    b1 = fmaxf(b1, 0.f);
    float a3 = g1 * a2;
    float d3 = g1 * d2 + b1;

    // GN 3 (ln1)
    float S3 = blockSum256(a3*sc + Tf*d3, red);
    float Q3 = blockSum256(a3*a3*qc + 2.f*a3*d3*sc + Tf*d3*d3, red);
    float mu3 = S3 * Ninv;
    float var3 = Q3 * Ninv - mu3 * mu3;
    float r3 = rsqrtf(var3 + EPSV);
    float w1 = ln1_w[c];
    float a4 = w1 * r3 * a3;
    float d4 = w1 * r3 * (d3 - mu3) + ln1_b[c];
    sh_a[c] = a4;
    sh_d[c] = d4;

    // cue2 = relu(cue @ cds_w.T)
    float c2 = 0.f;
    for (int k = 0; k < 512; ++k) c2 = fmaf(sh_cue[k], cds_w[c*512 + k], c2);
    sh_cue2[c] = fmaxf(c2, 0.f);
    __syncthreads();

    // film2 coefficients + e_o
    if (c < 128) {
        float g2 = f2g_b[c], b2 = f2b_b[c];
        for (int k = 0; k < 256; ++k) {
            const float cv = sh_cue2[k];
            g2 = fmaf(cv, f2g_w[c*256 + k], g2);
            b2 = fmaf(cv, f2b_w[c*256 + k], b2);
        }
        g2 = fmaxf(g2, 0.f) + 1.f;
        b2 = fmaxf(b2, 0.f);
        float u = 0.f;
        for (int k = 0; k < 256; ++k) u = fmaf(conv1_w[c*256 + k], sh_d[k], u);
        eout[b*128 + c] = g2 * u + b2;
        sh_g2[c] = g2;
    }
    __syncthreads();

    // M[o][c] = (1+g2_o) * conv1_w[o][c] * a4_c
    for (int o = 0; o < 128; ++o) {
        Mout[((size_t)b*128 + o)*256 + c] = sh_g2[o] * conv1_w[o*256 + c] * sh_a[c];
    }
}

// ---------------------------------------------------------------------------
// Kernel C / E shared body: y[o,t] = sum_c Mtx[o,c] * x[c,t]  (+ addv[o])
// STATS=true : reduce per-o sum / sumsq into s2p/q2p partials (kernel C)
// STATS=false: write y to outp (kernel E)
// block: 256 threads, tile = 128 o x 128 t, k-chunks of 64 channels.
// thread (og,tg) computes o = og*8..+7 ; t = tg*4..+3 and 64+tg*4..+3
// ---------------------------------------------------------------------------
template<bool STATS>
__global__ __launch_bounds__(256, 2) void kApplyMat(
    const float* __restrict__ x,
    const float* __restrict__ Mtx,     // [NB][OCtot][256]
    const float* __restrict__ addv,    // [NB][OCtot]
    float* __restrict__ outp,          // [NB][OCtot][T] or null
    float* __restrict__ s2p,           // [NB][NTB][128] or null
    float* __restrict__ q2p,
    int OCtot)
{
    const int tb  = blockIdx.x;        // 0..124
    const int b   = blockIdx.y;        // 0..15
    const int oc0 = blockIdx.z * 128;  // 0 or 128
    const int tid = threadIdx.x;
    const int og  = tid >> 4;          // 0..15
    const int tg  = tid & 15;          // 0..15
    const int t0  = tb * 128;

    __shared__ float Xs[64][128];      // 32 KB
    __shared__ float Mt[64][132];      // 33.8 KB (transposed, padded)

    float acc[8][8];
    #pragma unroll
    for (int i = 0; i < 8; ++i)
        #pragma unroll
        for (int j = 0; j < 8; ++j) acc[i][j] = 0.f;

    for (int ck = 0; ck < 256; ck += 64) {
        // stage X chunk [64c][128t]
        #pragma unroll
        for (int k = 0; k < 8; ++k) {
            const int i4 = tid + k*256;
            const int cr = i4 >> 5, ts = i4 & 31;
            const float4 v = *(const float4*)(x + ((size_t)b*256 + ck + cr)*T_LEN + t0 + ts*4);
            *(float4*)(&Xs[cr][ts*4]) = v;
        }
        // stage M chunk transposed: Mt[cc][o]
        #pragma unroll
        for (int k = 0; k < 8; ++k) {
            const int i4 = tid + k*256;
            const int o = i4 >> 4, c4 = i4 & 15;
            const float4 v = *(const float4*)(Mtx + ((size_t)b*OCtot + oc0 + o)*256 + ck + c4*4);
            Mt[c4*4 + 0][o] = v.x;
            Mt[c4*4 + 1][o] = v.y;
            Mt[c4*4 + 2][o] = v.z;
            Mt[c4*4 + 3][o] = v.w;
        }
        __syncthreads();

        #pragma unroll 2
        for (int cc = 0; cc < 64; ++cc) {
            const float4 xa = *(const float4*)(&Xs[cc][tg*4]);
            const float4 xb = *(const float4*)(&Xs[cc][64 + tg*4]);
            const float4 ma = *(const float4*)(&Mt[cc][og*8]);
            const float4 mb = *(const float4*)(&Mt[cc][og*8 + 4]);
            const float xv[8] = {xa.x, xa.y, xa.z, xa.w, xb.x, xb.y, xb.z, xb.w};
            const float mv[8] = {ma.x, ma.y, ma.z, ma.w, mb.x, mb.y, mb.z, mb.w};
            #pragma unroll
            for (int i = 0; i < 8; ++i)
                #pragma unroll
                for (int j = 0; j < 8; ++j)
                    acc[i][j] = fmaf(mv[i], xv[j], acc[i][j]);
        }
        __syncthreads();
    }

    if constexpr (STATS) {
        // z2 = acc + e_o ; partial sums over the 128-t tile
        float* redS = &Xs[0][0];               // reuse LDS: [128][17]
        float* redQ = &Xs[0][0] + 4096;
        #pragma unroll
        for (int i = 0; i < 8; ++i) {
            const int o = og*8 + i;
            const float ev = addv[b*OCtot + oc0 + o];
            float ps = 0.f, qs = 0.f;
            #pragma unroll
            for (int j = 0; j < 8; ++j) {
                const float z = acc[i][j] + ev;
                ps += z;
                qs += z*z;
            }
            redS[o*17 + tg] = ps;
            redQ[o*17 + tg] = qs;
        }
        __syncthreads();
        if (tid < 128) {
            float ps = 0.f, qs = 0.f;
            #pragma unroll
            for (int k = 0; k < 16; ++k) {
                ps += redS[tid*17 + k];
                qs += redQ[tid*17 + k];
            }
            s2p[((size_t)b*NTB + tb)*128 + tid] = ps;
            q2p[((size_t)b*NTB + tb)*128 + tid] = qs;
        }
    } else {
        #pragma unroll
        for (int i = 0; i < 8; ++i) {
            const int o = oc0 + og*8 + i;
            const float hv = addv[b*OCtot + o];
            float* op = outp + ((size_t)b*OCtot + o)*T_LEN + t0;
            float4 va = make_float4(acc[i][0]+hv, acc[i][1]+hv, acc[i][2]+hv, acc[i][3]+hv);
            float4 vb = make_float4(acc[i][4]+hv, acc[i][5]+hv, acc[i][6]+hv, acc[i][7]+hv);
            *(float4*)(op + tg*4) = va;
            *(float4*)(op + 64 + tg*4) = vb;
        }
    }
}

// ---------------------------------------------------------------------------
// Kernel D1: finalize GN-4 stats -> A2[b][o], D2[b][o].  16 blocks x 128 thr.
// ---------------------------------------------------------------------------
__global__ __launch_bounds__(128) void kD1_finalize(
    const float* __restrict__ s2p, const float* __restrict__ q2p,
    const float* __restrict__ ln2_w, const float* __restrict__ ln2_b,
    float* __restrict__ A2, float* __restrict__ D2)
{
    const int b = blockIdx.x;
    const int o = threadIdx.x;
    float s = 0.f, qq = 0.f;
    for (int tb = 0; tb < NTB; ++tb) {
        s  += s2p[((size_t)b*NTB + tb)*128 + o];
        qq += q2p[((size_t)b*NTB + tb)*128 + o];
    }
    float S = s, Q = qq;
    #pragma unroll
    for (int off = 32; off; off >>= 1) {
        S += __shfl_down(S, off, 64);
        Q += __shfl_down(Q, off, 64);
    }
    __shared__ float rS[2], rQ[2];
    if ((o & 63) == 0) { rS[o >> 6] = S; rQ[o >> 6] = Q; }
    __syncthreads();
    const float N2inv = 1.f / (128.f * 16000.f);
    const float mu  = (rS[0] + rS[1]) * N2inv;
    const float var = (rQ[0] + rQ[1]) * N2inv - mu * mu;
    const float r = rsqrtf(var + EPSV);
    A2[b*128 + o] = ln2_w[o] * r;
    D2[b*128 + o] = ln2_b[o] - mu * ln2_w[o] * r;
}

// ---------------------------------------------------------------------------
// Kernel D2: F[p][c] = sum_o conv2_w[p][o]*A2[o]*M[o][c];  h[p] = ...
// grid (8 pg, 16 b), 256 threads; thread = column c, covers 32 p rows.
// ---------------------------------------------------------------------------
__global__ __launch_bounds__(256) void kD2_buildF(
    const float* __restrict__ M, const float* __restrict__ e,
    const float* __restrict__ A2, const float* __restrict__ D2,
    const float* __restrict__ conv2_w,
    float* __restrict__ F, float* __restrict__ h)
{
    const int b = blockIdx.y, pg = blockIdx.x;
    const int tid = threadIdx.x;
    __shared__ float Qs[32][128];       // 16 KB
    #pragma unroll
    for (int k = 0; k < 16; ++k) {
        const int idx = tid + k*256;
        const int p = idx >> 7, o = idx & 127;
        Qs[p][o] = conv2_w[(pg*32 + p)*128 + o] * A2[b*128 + o];
    }
    __syncthreads();
    float acc[32];
    #pragma unroll
    for (int p = 0; p < 32; ++p) acc[p] = 0.f;
    for (int o = 0; o < 128; ++o) {
        const float mv = M[((size_t)b*128 + o)*256 + tid];
        #pragma unroll
        for (int p = 0; p < 32; ++p) acc[p] = fmaf(Qs[p][o], mv, acc[p]);
    }
    #pragma unroll
    for (int p = 0; p < 32; ++p)
        F[((size_t)b*256 + pg*32 + p)*256 + tid] = acc[p];
    if (tid < 32) {
        const int p = pg*32 + tid;
        float hv = 0.f;
        for (int o = 0; o < 128; ++o)
            hv += Qs[tid][o] * e[b*128 + o] + conv2_w[p*128 + o] * D2[b*128 + o];
        h[b*256 + p] = hv;
    }
}

// ---------------------------------------------------------------------------
extern "C" void kernel_launch(void* const* d_in, const int* in_sizes, int n_in,
                              void* d_out, int out_size, void* d_ws, size_t ws_size,
                              hipStream_t stream)
{
    const float* x       = (const float*)d_in[0];
    const float* cue     = (const float*)d_in[1];
    const float* gn_a_w  = (const float*)d_in[2];
    const float* gn_a_b  = (const float*)d_in[3];
    const float* gn_n_w  = (const float*)d_in[4];
    const float* gn_n_b  = (const float*)d_in[5];
    const float* f1g_w   = (const float*)d_in[6];
    const float* f1g_b   = (const float*)d_in[7];
    const float* f1b_w   = (const float*)d_in[8];
    const float* f1b_b   = (const float*)d_in[9];
    const float* ln1_w   = (const float*)d_in[10];
    const float* ln1_b   = (const float*)d_in[11];
    const float* conv1_w = (const float*)d_in[12];
    const float* cds_w   = (const float*)d_in[13];
    const float* f2g_w   = (const float*)d_in[14];
    const float* f2g_b   = (const float*)d_in[15];
    const float* f2b_w   = (const float*)d_in[16];
    const float* f2b_b   = (const float*)d_in[17];
    const float* ln2_w   = (const float*)d_in[18];
    const float* ln2_b   = (const float*)d_in[19];
    const float* conv2_w = (const float*)d_in[20];
    float* out = (float*)d_out;

    float* ws  = (float*)d_ws;
    float* s   = ws;                 // 16*256
    float* q   = s   + 4096;         // 16*256
    float* M   = q   + 4096;         // 16*128*256
    float* e   = M   + 524288;       // 16*128
    float* A2  = e   + 2048;         // 16*128
    float* D2  = A2  + 2048;         // 16*128
    float* F   = D2  + 2048;         // 16*256*256
    float* h   = F   + 1048576;      // 16*256
    float* s2p = h   + 4096;         // 16*125*128
    float* q2p = s2p + 256000;       // 16*125*128

    kA_rowstats<<<NB*C_IN, 256, 0, stream>>>(x, s, q);

    kB_compose<<<NB, 256, 0, stream>>>(s, q, cue,
        gn_a_w, gn_a_b, gn_n_w, gn_n_b,
        f1g_w, f1g_b, f1b_w, f1b_b, ln1_w, ln1_b,
        conv1_w, cds_w, f2g_w, f2g_b, f2b_w, f2b_b,
        M, e);

    kApplyMat<true><<<dim3(NTB, NB, 1), 256, 0, stream>>>(
        x, M, e, nullptr, s2p, q2p, 128);

    kD1_finalize<<<NB, 128, 0, stream>>>(s2p, q2p, ln2_w, ln2_b, A2, D2);

    kD2_buildF<<<dim3(8, NB), 256, 0, stream>>>(M, e, A2, D2, conv2_w, F, h);

    kApplyMat<false><<<dim3(NTB, NB, 2), 256, 0, stream>>>(
        x, F, h, out, nullptr, nullptr, 256);
}

// Round 2
// 506.072 us; speedup vs baseline: 1.6061x; 1.6061x over previous
//
#include <hip/hip_runtime.h>
#include <hip/hip_bf16.h>

#define T_LEN   16000
#define NT4     4000        // T_LEN/4
#define NB      16
#define NTB     125         // T_LEN / 128 (kC tiling)
#define NTE     250         // T_LEN / 64  (kE tiling)
#define EPSV    1e-8f

typedef short bf16x8 __attribute__((ext_vector_type(8)));
typedef float f32x4  __attribute__((ext_vector_type(4)));

__device__ __forceinline__ ushort bf16_rn(float f) {
    uint u = __float_as_uint(f);
    uint r = (u + 0x7FFFu + ((u >> 16) & 1u)) >> 16;
    return (ushort)r;
}
__device__ __forceinline__ float bf16_tof(ushort h) {
    return __uint_as_float(((uint)h) << 16);
}
__device__ __forceinline__ void bfsplit(float v, ushort& h, ushort& l) {
    h = bf16_rn(v);
    l = bf16_rn(v - bf16_tof(h));
}
__device__ __forceinline__ float f4c(const float4& v, int i) {
    return i == 0 ? v.x : i == 1 ? v.y : i == 2 ? v.z : v.w;
}
// LDS unit swizzle: spreads banks for both frag reads (t consecutive) and
// staging writes (t stride-4): f(t) = (t ^ (t>>3)) & 7
__device__ __forceinline__ int swz(int u, int t) {
    return u ^ ((t ^ (t >> 3)) & 7);
}

// ---------------------------------------------------------------------------
// Kernel A: per-(b,c) row sums s = sum(x), q = sum(x^2).  4096 blocks.
// ---------------------------------------------------------------------------
__global__ __launch_bounds__(256) void kA_rowstats(
    const float* __restrict__ x, float* __restrict__ s, float* __restrict__ q)
{
    const int row = blockIdx.x;                 // b*256 + c
    const float4* x4 = (const float4*)(x + (size_t)row * T_LEN);
    float ss = 0.f, qq = 0.f;
    for (int i = threadIdx.x; i < NT4; i += 256) {
        float4 v = x4[i];
        ss += v.x + v.y + v.z + v.w;
        qq += v.x*v.x + v.y*v.y + v.z*v.z + v.w*v.w;
    }
    #pragma unroll
    for (int off = 32; off; off >>= 1) {
        ss += __shfl_down(ss, off, 64);
        qq += __shfl_down(qq, off, 64);
    }
    __shared__ float rs[4], rq[4];
    const int wid = threadIdx.x >> 6, lane = threadIdx.x & 63;
    if (lane == 0) { rs[wid] = ss; rq[wid] = qq; }
    __syncthreads();
    if (threadIdx.x == 0) {
        s[row] = rs[0] + rs[1] + rs[2] + rs[3];
        q[row] = rq[0] + rq[1] + rq[2] + rq[3];
    }
}

// ---------------------------------------------------------------------------
__device__ __forceinline__ float blockSum256(float v, float* red)
{
    #pragma unroll
    for (int off = 32; off; off >>= 1) v += __shfl_down(v, off, 64);
    __syncthreads();
    if ((threadIdx.x & 63) == 0) red[threadIdx.x >> 6] = v;
    __syncthreads();
    return red[0] + red[1] + red[2] + red[3];
}

// ---------------------------------------------------------------------------
// Kernel B: analytic affine composition -> M (fp32 + bf16 hi/lo), e.
// ---------------------------------------------------------------------------
__global__ __launch_bounds__(256) void kB_compose(
    const float* __restrict__ s,      const float* __restrict__ q,
    const float* __restrict__ cue,
    const float* __restrict__ gn_a_w, const float* __restrict__ gn_a_b,
    const float* __restrict__ gn_n_w, const float* __restrict__ gn_n_b,
    const float* __restrict__ f1g_w,  const float* __restrict__ f1g_b,
    const float* __restrict__ f1b_w,  const float* __restrict__ f1b_b,
    const float* __restrict__ ln1_w,  const float* __restrict__ ln1_b,
    const float* __restrict__ conv1_w,const float* __restrict__ cds_w,
    const float* __restrict__ f2g_w,  const float* __restrict__ f2g_b,
    const float* __restrict__ f2b_w,  const float* __restrict__ f2b_b,
    float* __restrict__ Mout, ushort* __restrict__ Mh, ushort* __restrict__ Ml,
    float* __restrict__ eout)
{
    const int b = blockIdx.x;
    const int c = threadIdx.x;           // 0..255
    __shared__ float red[4];
    __shared__ float sh_cue[512];
    __shared__ float sh_a[256], sh_d[256], sh_cue2[256], sh_g2[128];

    sh_cue[c]       = cue[b*512 + c];
    sh_cue[256 + c] = cue[b*512 + 256 + c];
    const float sc = s[b*256 + c];
    const float qc = q[b*256 + c];
    __syncthreads();

    const float Ninv = 1.f / (256.f * 16000.f);
    const float Tf = 16000.f;

    float S  = blockSum256(sc, red);
    float Q  = blockSum256(qc, red);
    float mu1 = S * Ninv;
    float var1 = Q * Ninv - mu1 * mu1;
    float r1 = rsqrtf(var1 + EPSV);
    float a1 = gn_a_w[c] * r1;
    float d1 = gn_a_b[c] - mu1 * r1 * gn_a_w[c];

    float S2 = blockSum256(a1*sc + Tf*d1, red);
    float Q2 = blockSum256(a1*a1*qc + 2.f*a1*d1*sc + Tf*d1*d1, red);
    float mu2 = S2 * Ninv;
    float var2 = Q2 * Ninv - mu2 * mu2;
    float r2 = rsqrtf(var2 + EPSV);
    float wn = gn_n_w[c];
    float a2 = wn * r2 * a1;
    float d2 = wn * r2 * (d1 - mu2) + gn_n_b[c];

    float g1 = f1g_b[c], b1 = f1b_b[c];
    for (int k = 0; k < 512; ++k) {
        const float cv = sh_cue[k];
        g1 = fmaf(cv, f1g_w[c*512 + k], g1);
        b1 = fmaf(cv, f1b_w[c*512 + k], b1);
    }
    g1 = fmaxf(g1, 0.f) + 1.f;
    b1 = fmaxf(b1, 0.f);
    float a3 = g1 * a2;
    float d3 = g1 * d2 + b1;

    float S3 = blockSum256(a3*sc + Tf*d3, red);
    float Q3 = blockSum256(a3*a3*qc + 2.f*a3*d3*sc + Tf*d3*d3, red);
    float mu3 = S3 * Ninv;
    float var3 = Q3 * Ninv - mu3 * mu3;
    float r3 = rsqrtf(var3 + EPSV);
    float w1 = ln1_w[c];
    float a4 = w1 * r3 * a3;
    float d4 = w1 * r3 * (d3 - mu3) + ln1_b[c];
    sh_a[c] = a4;
    sh_d[c] = d4;

    float c2 = 0.f;
    for (int k = 0; k < 512; ++k) c2 = fmaf(sh_cue[k], cds_w[c*512 + k], c2);
    sh_cue2[c] = fmaxf(c2, 0.f);
    __syncthreads();

    if (c < 128) {
        float g2 = f2g_b[c], b2 = f2b_b[c];
        for (int k = 0; k < 256; ++k) {
            const float cv = sh_cue2[k];
            g2 = fmaf(cv, f2g_w[c*256 + k], g2);
            b2 = fmaf(cv, f2b_w[c*256 + k], b2);
        }
        g2 = fmaxf(g2, 0.f) + 1.f;
        b2 = fmaxf(b2, 0.f);
        float u = 0.f;
        for (int k = 0; k < 256; ++k) u = fmaf(conv1_w[c*256 + k], sh_d[k], u);
        eout[b*128 + c] = g2 * u + b2;
        sh_g2[c] = g2;
    }
    __syncthreads();

    for (int o = 0; o < 128; ++o) {
        const float m = sh_g2[o] * conv1_w[o*256 + c] * sh_a[c];
        const size_t idx = ((size_t)b*128 + o)*256 + c;
        Mout[idx] = m;
        ushort hh, ll; bfsplit(m, hh, ll);
        Mh[idx] = hh; Ml[idx] = ll;
    }
}

// ---------------------------------------------------------------------------
// Kernel C (MFMA): z2 = M x + e stats.  Tile 128o x 128t, 4 waves (2o x 2t).
// X transposed+split into LDS (dbuf); M hi/lo fragments direct from global.
// ---------------------------------------------------------------------------
__global__ __launch_bounds__(256, 2) void kC_mfma(
    const float* __restrict__ x,
    const ushort* __restrict__ Mh, const ushort* __restrict__ Ml,
    const float* __restrict__ e,
    float* __restrict__ s2p, float* __restrict__ q2p)
{
    const int tb = blockIdx.x;         // 0..124
    const int b  = blockIdx.y;         // 0..15
    const int tid  = threadIdx.x;
    const int lane = tid & 63;
    const int wid  = tid >> 6;
    const int o0w = (wid >> 1) * 64;   // 0 or 64
    const int t0w = (wid & 1) * 64;    // 0 or 64
    const int sub = lane >> 4;         // 0..3
    const int li  = lane & 15;
    const int t0  = tb * 128;

    __shared__ uint4 XsH[2][128*8];    // 32 KB
    __shared__ uint4 XsL[2][128*8];    // 32 KB
    __shared__ float sSp[2][128], sQp[2][128];

    f32x4 acc[4][4];
    #pragma unroll
    for (int i = 0; i < 4; ++i)
        #pragma unroll
        for (int j = 0; j < 4; ++j) acc[i][j] = (f32x4){0.f, 0.f, 0.f, 0.f};

    const int g  = tid >> 5;           // 0..7  (owns c = g*8..g*8+7)
    const int t4 = tid & 31;           // t = t4*4..+3

    float4 xr[8];
    #pragma unroll
    for (int k = 0; k < 8; ++k)
        xr[k] = *(const float4*)(x + ((size_t)(b*256 + g*8 + k))*T_LEN + t0 + t4*4);

    for (int ck = 0; ck < 4; ++ck) {
        const int buf = ck & 1;
        // ---- convert + transpose-write into LDS (own full 16B unit u=g) ----
        #pragma unroll
        for (int i = 0; i < 4; ++i) {
            const int t = t4*4 + i;
            uint hh[4], ll[4];
            #pragma unroll
            for (int d = 0; d < 4; ++d) {
                ushort ha, la, hb, lb;
                bfsplit(f4c(xr[2*d],   i), ha, la);
                bfsplit(f4c(xr[2*d+1], i), hb, lb);
                hh[d] = (uint)ha | ((uint)hb << 16);
                ll[d] = (uint)la | ((uint)lb << 16);
            }
            const int idx = t*8 + swz(g, t);
            XsH[buf][idx] = (uint4){hh[0], hh[1], hh[2], hh[3]};
            XsL[buf][idx] = (uint4){ll[0], ll[1], ll[2], ll[3]};
        }
        if (ck < 3) {
            #pragma unroll
            for (int k = 0; k < 8; ++k)
                xr[k] = *(const float4*)(x + ((size_t)(b*256 + (ck+1)*64 + g*8 + k))*T_LEN + t0 + t4*4);
        }
        __syncthreads();
        // ---- compute: 2 k-slices of 32 ----
        #pragma unroll
        for (int ks = 0; ks < 2; ++ks) {
            const int kkg = ck*64 + ks*32 + 8*sub;   // absolute k for this lane
            const int uo  = ks*4 + sub;              // LDS unit index
            bf16x8 bh[4], bl[4];
            #pragma unroll
            for (int ft = 0; ft < 4; ++ft) {
                const int t = t0w + ft*16 + li;
                const int idx = t*8 + swz(uo, t);
                bh[ft] = *(const bf16x8*)&XsH[buf][idx];
                bl[ft] = *(const bf16x8*)&XsL[buf][idx];
            }
            #pragma unroll
            for (int fo = 0; fo < 4; ++fo) {
                const int o = o0w + fo*16 + li;
                const size_t base = ((size_t)(b*128 + o))*256 + kkg;
                bf16x8 ah = *(const bf16x8*)(Mh + base);
                bf16x8 al = *(const bf16x8*)(Ml + base);
                #pragma unroll
                for (int ft = 0; ft < 4; ++ft) {
                    acc[fo][ft] = __builtin_amdgcn_mfma_f32_16x16x32_bf16(ah, bh[ft], acc[fo][ft], 0, 0, 0);
                    acc[fo][ft] = __builtin_amdgcn_mfma_f32_16x16x32_bf16(al, bh[ft], acc[fo][ft], 0, 0, 0);
                    acc[fo][ft] = __builtin_amdgcn_mfma_f32_16x16x32_bf16(ah, bl[ft], acc[fo][ft], 0, 0, 0);
                }
            }
        }
        __syncthreads();
    }

    // ---- stats: z = acc + e[o]; per-o sum/sumsq over this 128-t tile ----
    #pragma unroll
    for (int fo = 0; fo < 4; ++fo) {
        #pragma unroll
        for (int r = 0; r < 4; ++r) {
            const int o = o0w + fo*16 + sub*4 + r;
            const float ev = e[b*128 + o];
            float sv = 0.f, qv = 0.f;
            #pragma unroll
            for (int ft = 0; ft < 4; ++ft) {
                const float z = acc[fo][ft][r] + ev;
                sv += z; qv += z*z;
            }
            #pragma unroll
            for (int m = 1; m <= 8; m <<= 1) {
                sv += __shfl_xor(sv, m, 64);
                qv += __shfl_xor(qv, m, 64);
            }
            if (li == 0) { sSp[wid & 1][o] = sv; sQp[wid & 1][o] = qv; }
        }
    }
    __syncthreads();
    if (tid < 128) {
        s2p[((size_t)b*NTB + tb)*128 + tid] = sSp[0][tid] + sSp[1][tid];
        q2p[((size_t)b*NTB + tb)*128 + tid] = sQp[0][tid] + sQp[1][tid];
    }
}

// ---------------------------------------------------------------------------
// Kernel D1: finalize GN-4 stats -> A2, D2.
// ---------------------------------------------------------------------------
__global__ __launch_bounds__(128) void kD1_finalize(
    const float* __restrict__ s2p, const float* __restrict__ q2p,
    const float* __restrict__ ln2_w, const float* __restrict__ ln2_b,
    float* __restrict__ A2, float* __restrict__ D2)
{
    const int b = blockIdx.x;
    const int o = threadIdx.x;
    float s = 0.f, qq = 0.f;
    for (int tb = 0; tb < NTB; ++tb) {
        s  += s2p[((size_t)b*NTB + tb)*128 + o];
        qq += q2p[((size_t)b*NTB + tb)*128 + o];
    }
    float S = s, Q = qq;
    #pragma unroll
    for (int off = 32; off; off >>= 1) {
        S += __shfl_down(S, off, 64);
        Q += __shfl_down(Q, off, 64);
    }
    __shared__ float rS[2], rQ[2];
    if ((o & 63) == 0) { rS[o >> 6] = S; rQ[o >> 6] = Q; }
    __syncthreads();
    const float N2inv = 1.f / (128.f * 16000.f);
    const float mu  = (rS[0] + rS[1]) * N2inv;
    const float var = (rQ[0] + rQ[1]) * N2inv - mu * mu;
    const float r = rsqrtf(var + EPSV);
    A2[b*128 + o] = ln2_w[o] * r;
    D2[b*128 + o] = ln2_b[o] - mu * ln2_w[o] * r;
}

// ---------------------------------------------------------------------------
// Kernel D2: F = conv2 * diag(A2) * M  (bf16 hi/lo planes) ; h vector.
// ---------------------------------------------------------------------------
__global__ __launch_bounds__(256) void kD2_buildF(
    const float* __restrict__ M, const float* __restrict__ e,
    const float* __restrict__ A2, const float* __restrict__ D2,
    const float* __restrict__ conv2_w,
    ushort* __restrict__ Fh, ushort* __restrict__ Fl, float* __restrict__ h)
{
    const int b = blockIdx.y, pg = blockIdx.x;
    const int tid = threadIdx.x;
    __shared__ float Qs[32][128];
    #pragma unroll
    for (int k = 0; k < 16; ++k) {
        const int idx = tid + k*256;
        const int p = idx >> 7, o = idx & 127;
        Qs[p][o] = conv2_w[(pg*32 + p)*128 + o] * A2[b*128 + o];
    }
    __syncthreads();
    float acc[32];
    #pragma unroll
    for (int p = 0; p < 32; ++p) acc[p] = 0.f;
    for (int o = 0; o < 128; ++o) {
        const float mv = M[((size_t)b*128 + o)*256 + tid];
        #pragma unroll
        for (int p = 0; p < 32; ++p) acc[p] = fmaf(Qs[p][o], mv, acc[p]);
    }
    #pragma unroll
    for (int p = 0; p < 32; ++p) {
        const size_t idx = ((size_t)b*256 + pg*32 + p)*256 + tid;
        ushort hh, ll; bfsplit(acc[p], hh, ll);
        Fh[idx] = hh; Fl[idx] = ll;
    }
    if (tid < 32) {
        const int p = pg*32 + tid;
        float hv = 0.f;
        for (int o = 0; o < 128; ++o)
            hv += Qs[tid][o] * e[b*128 + o] + conv2_w[p*128 + o] * D2[b*128 + o];
        h[b*256 + p] = hv;
    }
}

// ---------------------------------------------------------------------------
// Kernel E (MFMA): out = F x + h.  Tile 256o x 64t, 4 waves (4o x 1t).
// ---------------------------------------------------------------------------
__global__ __launch_bounds__(256, 2) void kE_mfma(
    const float* __restrict__ x,
    const ushort* __restrict__ Fh, const ushort* __restrict__ Fl,
    const float* __restrict__ h,
    float* __restrict__ out)
{
    const int tb = blockIdx.x;         // 0..249
    const int b  = blockIdx.y;
    const int tid  = threadIdx.x;
    const int lane = tid & 63;
    const int wid  = tid >> 6;
    const int o0w = wid * 64;
    const int sub = lane >> 4;
    const int li  = lane & 15;
    const int t0  = tb * 64;

    __shared__ uint4 XsH[2][64*8];     // 16 KB
    __shared__ uint4 XsL[2][64*8];     // 16 KB

    f32x4 acc[4][4];                   // [fo][ft]
    #pragma unroll
    for (int i = 0; i < 4; ++i)
        #pragma unroll
        for (int j = 0; j < 4; ++j) acc[i][j] = (f32x4){0.f, 0.f, 0.f, 0.f};

    const int g  = tid >> 4;           // 0..15 (owns c = g*4..g*4+3)
    const int t4 = tid & 15;           // t = t4*4..+3
    const int u  = g >> 1;             // 16B unit shared with partner tid^16

    float4 xr[4];
    #pragma unroll
    for (int k = 0; k < 4; ++k)
        xr[k] = *(const float4*)(x + ((size_t)(b*256 + g*4 + k))*T_LEN + t0 + t4*4);

    for (int ck = 0; ck < 4; ++ck) {
        const int buf = ck & 1;
        #pragma unroll
        for (int i = 0; i < 4; ++i) {
            const int t = t4*4 + i;
            ushort h0, l0, h1, l1, h2, l2, h3, l3;
            bfsplit(f4c(xr[0], i), h0, l0);
            bfsplit(f4c(xr[1], i), h1, l1);
            bfsplit(f4c(xr[2], i), h2, l2);
            bfsplit(f4c(xr[3], i), h3, l3);
            uint hA = (uint)h0 | ((uint)h1 << 16);
            uint hB = (uint)h2 | ((uint)h3 << 16);
            uint lA = (uint)l0 | ((uint)l1 << 16);
            uint lB = (uint)l2 | ((uint)l3 << 16);
            // partner exchange: tid^16 holds the other half of unit u
            uint phA = (uint)__shfl_xor((int)hA, 16, 64);
            uint phB = (uint)__shfl_xor((int)hB, 16, 64);
            uint plA = (uint)__shfl_xor((int)lA, 16, 64);
            uint plB = (uint)__shfl_xor((int)lB, 16, 64);
            const int idx = t*8 + swz(u, t);
            if ((g & 1) == 0) XsH[buf][idx] = (uint4){hA, hB, phA, phB};
            else              XsL[buf][idx] = (uint4){plA, plB, lA, lB};
        }
        if (ck < 3) {
            #pragma unroll
            for (int k = 0; k < 4; ++k)
                xr[k] = *(const float4*)(x + ((size_t)(b*256 + (ck+1)*64 + g*4 + k))*T_LEN + t0 + t4*4);
        }
        __syncthreads();
        #pragma unroll
        for (int ks = 0; ks < 2; ++ks) {
            const int kkg = ck*64 + ks*32 + 8*sub;
            const int uo  = ks*4 + sub;
            bf16x8 bh[4], bl[4];
            #pragma unroll
            for (int ft = 0; ft < 4; ++ft) {
                const int t = ft*16 + li;
                const int idx = t*8 + swz(uo, t);
                bh[ft] = *(const bf16x8*)&XsH[buf][idx];
                bl[ft] = *(const bf16x8*)&XsL[buf][idx];
            }
            #pragma unroll
            for (int fo = 0; fo < 4; ++fo) {
                const int o = o0w + fo*16 + li;
                const size_t base = ((size_t)(b*256 + o))*256 + kkg;
                bf16x8 ah = *(const bf16x8*)(Fh + base);
                bf16x8 al = *(const bf16x8*)(Fl + base);
                #pragma unroll
                for (int ft = 0; ft < 4; ++ft) {
                    acc[fo][ft] = __builtin_amdgcn_mfma_f32_16x16x32_bf16(ah, bh[ft], acc[fo][ft], 0, 0, 0);
                    acc[fo][ft] = __builtin_amdgcn_mfma_f32_16x16x32_bf16(al, bh[ft], acc[fo][ft], 0, 0, 0);
                    acc[fo][ft] = __builtin_amdgcn_mfma_f32_16x16x32_bf16(ah, bl[ft], acc[fo][ft], 0, 0, 0);
                }
            }
        }
        __syncthreads();
    }

    // epilogue: out = acc + h[o]
    float hv[4][4];
    #pragma unroll
    for (int fo = 0; fo < 4; ++fo)
        #pragma unroll
        for (int r = 0; r < 4; ++r)
            hv[fo][r] = h[b*256 + o0w + fo*16 + sub*4 + r];
    #pragma unroll
    for (int fo = 0; fo < 4; ++fo) {
        #pragma unroll
        for (int ft = 0; ft < 4; ++ft) {
            #pragma unroll
            for (int r = 0; r < 4; ++r) {
                const int o = o0w + fo*16 + sub*4 + r;
                out[((size_t)(b*256 + o))*T_LEN + t0 + ft*16 + li] = acc[fo][ft][r] + hv[fo][r];
            }
        }
    }
}

// ---------------------------------------------------------------------------
extern "C" void kernel_launch(void* const* d_in, const int* in_sizes, int n_in,
                              void* d_out, int out_size, void* d_ws, size_t ws_size,
                              hipStream_t stream)
{
    const float* x       = (const float*)d_in[0];
    const float* cue     = (const float*)d_in[1];
    const float* gn_a_w  = (const float*)d_in[2];
    const float* gn_a_b  = (const float*)d_in[3];
    const float* gn_n_w  = (const float*)d_in[4];
    const float* gn_n_b  = (const float*)d_in[5];
    const float* f1g_w   = (const float*)d_in[6];
    const float* f1g_b   = (const float*)d_in[7];
    const float* f1b_w   = (const float*)d_in[8];
    const float* f1b_b   = (const float*)d_in[9];
    const float* ln1_w   = (const float*)d_in[10];
    const float* ln1_b   = (const float*)d_in[11];
    const float* conv1_w = (const float*)d_in[12];
    const float* cds_w   = (const float*)d_in[13];
    const float* f2g_w   = (const float*)d_in[14];
    const float* f2g_b   = (const float*)d_in[15];
    const float* f2b_w   = (const float*)d_in[16];
    const float* f2b_b   = (const float*)d_in[17];
    const float* ln2_w   = (const float*)d_in[18];
    const float* ln2_b   = (const float*)d_in[19];
    const float* conv2_w = (const float*)d_in[20];
    float* out = (float*)d_out;

    float* ws  = (float*)d_ws;
    float* s    = ws;                   // 4096
    float* q    = ws + 4096;            // 4096
    float* M    = ws + 8192;            // 524288
    float* e    = ws + 532480;          // 2048
    float* A2   = ws + 534528;          // 2048
    float* D2   = ws + 536576;          // 2048
    float* h    = ws + 538624;          // 4096
    float* s2p  = ws + 542720;          // 256000
    float* q2p  = ws + 798720;          // 256000
    ushort* Mh  = (ushort*)(ws + 1054720);  // 16*128*256
    ushort* Ml  = (ushort*)(ws + 1316864);
    ushort* Fh  = (ushort*)(ws + 1579008);  // 16*256*256
    ushort* Fl  = (ushort*)(ws + 2103296);  // end: 2627584 floats (~10.5 MB)

    kA_rowstats<<<NB*256, 256, 0, stream>>>(x, s, q);

    kB_compose<<<NB, 256, 0, stream>>>(s, q, cue,
        gn_a_w, gn_a_b, gn_n_w, gn_n_b,
        f1g_w, f1g_b, f1b_w, f1b_b, ln1_w, ln1_b,
        conv1_w, cds_w, f2g_w, f2g_b, f2b_w, f2b_b,
        M, Mh, Ml, e);

    kC_mfma<<<dim3(NTB, NB), 256, 0, stream>>>(x, Mh, Ml, e, s2p, q2p);

    kD1_finalize<<<NB, 128, 0, stream>>>(s2p, q2p, ln2_w, ln2_b, A2, D2);

    kD2_buildF<<<dim3(8, NB), 256, 0, stream>>>(M, e, A2, D2, conv2_w, Fh, Fl, h);

    kE_mfma<<<dim3(NTE, NB), 256, 0, stream>>>(x, Fh, Fl, h, out);
}